// Round 2
// baseline (62.055 us; speedup 1.0000x reference)
//
#include <hip/hip_runtime.h>

// Depthwise 4x4 FIR blur, pad=(2,1) both H and W, fp32.
// x: [32, 256, 64, 64], kernel: [4,4], out: [32, 256, 64, 64].
// One block per (n,c) plane; plane staged in padded LDS.
// LDS-pipe diet vs R0: b128 reads (conflict-free at stride 68),
// border-only zeroing, single barrier, streaming row window (~45 VGPR).

#define SM_STRIDE 68   // 17 float4 per row; row-to-row offset = 4 banks
#define SM_ROWS   67   // 64 + pad_before(2) + pad_after(1)

__global__ __launch_bounds__(256, 8) void Blur_910533066888_kernel(
    const float* __restrict__ x,
    const float* __restrict__ k,
    float* __restrict__ out)
{
    __shared__ float sm[SM_ROWS * SM_STRIDE];

    const int t = threadIdx.x;
    const int plane = blockIdx.x;                 // n*C + c
    const float* __restrict__ xin = x + (size_t)plane * 4096;
    float* __restrict__ op = out + (size_t)plane * 4096;

    // --- stage the 64x64 plane into sm[row+2][col+2] (2x ds_write_b64) ---
    #pragma unroll
    for (int it = 0; it < 4; ++it) {
        int f4  = t + it * 256;        // float4 index in [0,1024)
        int row = f4 >> 4;
        int col = (f4 & 15) << 2;
        float4 v = reinterpret_cast<const float4*>(xin)[f4];
        float2* d = reinterpret_cast<float2*>(&sm[(row + 2) * SM_STRIDE + (col + 2)]);
        d[0] = make_float2(v.x, v.y);
        d[1] = make_float2(v.z, v.w);
    }

    // --- zero ONLY the border (disjoint from data region -> no extra barrier) ---
    {
        const float4 z4 = make_float4(0.f, 0.f, 0.f, 0.f);
        const float2 z2 = make_float2(0.f, 0.f);
        if (t < 34) {
            // rows 0-1: floats [0,136) = 34 float4
            reinterpret_cast<float4*>(sm)[t] = z4;
        } else if (t < 51) {
            // row 66: floats [4488,4556) = 17 float4
            reinterpret_cast<float4*>(sm)[1122 + (t - 34)] = z4;
        } else if (t >= 64 && t < 128) {
            // rows 2..65, left cols 0-1
            int r = t - 62;
            *reinterpret_cast<float2*>(&sm[r * SM_STRIDE]) = z2;
        } else if (t >= 128 && t < 192) {
            // rows 2..65, right cols 66-67
            int r = t - 126;
            *reinterpret_cast<float2*>(&sm[r * SM_STRIDE + 66]) = z2;
        }
    }

    __syncthreads();

    const int ty = (t >> 4) << 2;      // output row base (0..60)
    const int tx = (t & 15) << 2;      // output col base (0..60)

    // out[y][x] = sum_{i,j} kf[i][j] * xp[y+i][x+j],  kf[i][j] = k[3-i][3-j]
    // xp row/col c lives at sm row/col c (data stored at +2, pad_before = 2).
    float acc[4][4];
    #pragma unroll
    for (int a = 0; a < 4; ++a)
        #pragma unroll
        for (int b = 0; b < 4; ++b)
            acc[a][b] = 0.f;

    #pragma unroll
    for (int r = 0; r < 7; ++r) {      // xp rows ty..ty+6, streamed
        const float* srow = &sm[(ty + r) * SM_STRIDE + tx];
        float4 w0 = *reinterpret_cast<const float4*>(srow);      // cols tx..tx+3
        float4 w1 = *reinterpret_cast<const float4*>(srow + 4);  // cols tx+4..tx+7
        float wr[8] = {w0.x, w0.y, w0.z, w0.w, w1.x, w1.y, w1.z, w1.w};
        #pragma unroll
        for (int orow = 0; orow < 4; ++orow) {
            const int i = r - orow;    // tap row index
            if (i < 0 || i > 3) continue;
            #pragma unroll
            for (int j = 0; j < 4; ++j) {
                const float w = k[(3 - i) * 4 + (3 - j)];  // uniform -> scalar load
                #pragma unroll
                for (int c = 0; c < 4; ++c)
                    acc[orow][c] = fmaf(w, wr[j + c], acc[orow][c]);
            }
        }
    }

    #pragma unroll
    for (int orow = 0; orow < 4; ++orow) {
        float4 o = make_float4(acc[orow][0], acc[orow][1], acc[orow][2], acc[orow][3]);
        *reinterpret_cast<float4*>(&op[(ty + orow) * 64 + tx]) = o;
    }
}

extern "C" void kernel_launch(void* const* d_in, const int* in_sizes, int n_in,
                              void* d_out, int out_size, void* d_ws, size_t ws_size,
                              hipStream_t stream)
{
    const float* x = (const float*)d_in[0];
    const float* k = (const float*)d_in[1];
    float* out = (float*)d_out;

    const int planes = 32 * 256;   // N*C
    Blur_910533066888_kernel<<<planes, 256, 0, stream>>>(x, k, out);
}

// Round 3
// 44.002 us; speedup vs baseline: 1.4103x; 1.4103x over previous
//
#include <hip/hip_runtime.h>

// Depthwise 4x4 FIR blur, pad=(2,1) both H and W, fp32, SEPARABLE form.
// x: [32, 256, 64, 64], kernel: [4,4] (rank-1 by construction), out: same as x.
// One block (256 thr) per (n,c) plane.
//   Pass 1 (rowpass): global -> registers, horizontal FIR, write y[67][64] to LDS.
//   Pass 2 (colpass): 7x ds_read_b128 per thread, vertical FIR, float4 stores.
// LDS ops/thread ~12 (was 83); all LDS patterns balanced across bank groups.

#define ST 68   // float stride of y tile (17 float4; rows hit rotating bank groups)

__global__ __launch_bounds__(256, 8) void Blur_910533066888_kernel(
    const float* __restrict__ x,
    const float* __restrict__ k,
    float* __restrict__ out)
{
    __shared__ float sm[67 * ST];   // y[R][c], R in 0..66, c in 0..63

    const int t = threadIdx.x;
    const int plane = blockIdx.x;                 // n*C + c
    const float* __restrict__ xin = x + (size_t)plane * 4096;
    float* __restrict__ op = out + (size_t)plane * 4096;

    // Separable taps: kf[i][j] = k[3-i][3-j] = khf[i] * kwf[j]  (k is rank-1).
    // kwf = {1,3,3,1} exactly, khf = {1,3,3,1}/16 exactly for this kernel.
    const float inv = 1.0f / k[15];
    const float kw0 = k[15] * inv, kw1 = k[14] * inv, kw2 = k[13] * inv, kw3 = k[12] * inv;
    const float kh0 = k[15], kh1 = k[11], kh2 = k[7], kh3 = k[3];

    // ---- rowpass: thread t computes y[rx+2][cq .. cq+16) ----
    const int rx = t >> 2;            // x row 0..63  (y row rx+2, rows 2..65)
    const int q  = t & 3;             // column quarter
    const int cq = q << 4;
    const float* xrow = xin + rx * 64 + cq;

    float4 v0 = make_float4(0.f, 0.f, 0.f, 0.f);
    float4 v5 = make_float4(0.f, 0.f, 0.f, 0.f);
    if (q > 0) v0 = *reinterpret_cast<const float4*>(xrow - 4);   // left halo
    float4 v1 = *reinterpret_cast<const float4*>(xrow);
    float4 v2 = *reinterpret_cast<const float4*>(xrow + 4);
    float4 v3 = *reinterpret_cast<const float4*>(xrow + 8);
    float4 v4 = *reinterpret_cast<const float4*>(xrow + 12);
    if (q < 3) v5 = *reinterpret_cast<const float4*>(xrow + 16);  // right halo

    // y rows 0,1,66 are identically zero (zero-pad rows): fill while loads fly.
    if (t < 48) {
        int zr = t >> 4;
        zr = (zr == 2) ? 66 : zr;
        *reinterpret_cast<float4*>(&sm[zr * ST + ((t & 15) << 2)]) =
            make_float4(0.f, 0.f, 0.f, 0.f);
    }

    // xv[m] = x[rx][cq - 4 + m] (zero outside plane)
    float xv[24] = {
        v0.x, v0.y, v0.z, v0.w,  v1.x, v1.y, v1.z, v1.w,
        v2.x, v2.y, v2.z, v2.w,  v3.x, v3.y, v3.z, v3.w,
        v4.x, v4.y, v4.z, v4.w,  v5.x, v5.y, v5.z, v5.w };

    // y[rx+2][cq+u] = sum_j kwf[j] * x[rx][cq+u+j-2]  -> xv[u+2+j]
    float* yd = &sm[(rx + 2) * ST + cq];
    #pragma unroll
    for (int g = 0; g < 4; ++g) {
        float4 yq;
        float* yp = &yq.x;
        #pragma unroll
        for (int e = 0; e < 4; ++e) {
            const int u = g * 4 + e;
            yp[e] = fmaf(kw0, xv[u + 2],
                    fmaf(kw1, xv[u + 3],
                    fmaf(kw2, xv[u + 4], kw3 * xv[u + 5])));
        }
        *reinterpret_cast<float4*>(yd + 4 * g) = yq;
    }

    __syncthreads();

    // ---- colpass: thread t computes out[ty..ty+3][tx..tx+3] ----
    const int ty = (t >> 4) << 2;     // 0..60
    const int tx = (t & 15) << 2;     // 0..60

    float4 w[7];
    #pragma unroll
    for (int s = 0; s < 7; ++s)
        w[s] = *reinterpret_cast<const float4*>(&sm[(ty + s) * ST + tx]);

    #pragma unroll
    for (int r = 0; r < 4; ++r) {
        float4 o;
        o.x = fmaf(kh0, w[r].x, fmaf(kh1, w[r+1].x, fmaf(kh2, w[r+2].x, kh3 * w[r+3].x)));
        o.y = fmaf(kh0, w[r].y, fmaf(kh1, w[r+1].y, fmaf(kh2, w[r+2].y, kh3 * w[r+3].y)));
        o.z = fmaf(kh0, w[r].z, fmaf(kh1, w[r+1].z, fmaf(kh2, w[r+2].z, kh3 * w[r+3].z)));
        o.w = fmaf(kh0, w[r].w, fmaf(kh1, w[r+1].w, fmaf(kh2, w[r+2].w, kh3 * w[r+3].w)));
        *reinterpret_cast<float4*>(&op[(ty + r) * 64 + tx]) = o;
    }
}

extern "C" void kernel_launch(void* const* d_in, const int* in_sizes, int n_in,
                              void* d_out, int out_size, void* d_ws, size_t ws_size,
                              hipStream_t stream)
{
    const float* x = (const float*)d_in[0];
    const float* k = (const float*)d_in[1];
    float* out = (float*)d_out;

    const int planes = 32 * 256;   // N*C
    Blur_910533066888_kernel<<<planes, 256, 0, stream>>>(x, k, out);
}

// Round 5
// 43.169 us; speedup vs baseline: 1.4375x; 1.0193x over previous
//
#include <hip/hip_runtime.h>

// Depthwise 4x4 FIR blur, pad=(2,1) both H and W, fp32, SEPARABLE form.
// x: [32, 256, 64, 64], kernel: [4,4] (rank-1 by construction), out: same as x.
// One block (256 thr) per (n,c) plane.
//   Pass 1 (rowpass): global -> registers, horizontal FIR, write y[67][64] to LDS.
//   Pass 2 (colpass): 7x ds_read_b128 per thread, vertical FIR, float4 stores.
// R4: NON-TEMPORAL output stores via native vector type (fixes R3 compile
// error) -> keep the 128 MiB input L3-resident; input+output = 256 MiB
// exactly thrashes the Infinity Cache with regular stores.

#define ST 68   // float stride of y tile (17 float4; rows hit rotating bank groups)

typedef float f32x4 __attribute__((ext_vector_type(4)));

__global__ __launch_bounds__(256, 8) void Blur_910533066888_kernel(
    const float* __restrict__ x,
    const float* __restrict__ k,
    float* __restrict__ out)
{
    __shared__ float sm[67 * ST];   // y[R][c], R in 0..66, c in 0..63

    const int t = threadIdx.x;
    const int plane = blockIdx.x;                 // n*C + c
    const float* __restrict__ xin = x + (size_t)plane * 4096;
    float* __restrict__ op = out + (size_t)plane * 4096;

    // Separable taps: kf[i][j] = k[3-i][3-j] = khf[i] * kwf[j]  (k is rank-1).
    // kwf = {1,3,3,1} exactly, khf = {1,3,3,1}/16 exactly for this kernel.
    const float inv = 1.0f / k[15];
    const float kw0 = k[15] * inv, kw1 = k[14] * inv, kw2 = k[13] * inv, kw3 = k[12] * inv;
    const float kh0 = k[15], kh1 = k[11], kh2 = k[7], kh3 = k[3];

    // ---- rowpass: thread t computes y[rx+2][cq .. cq+16) ----
    const int rx = t >> 2;            // x row 0..63  (y row rx+2, rows 2..65)
    const int q  = t & 3;             // column quarter
    const int cq = q << 4;
    const float* xrow = xin + rx * 64 + cq;

    float4 v0 = make_float4(0.f, 0.f, 0.f, 0.f);
    float4 v5 = make_float4(0.f, 0.f, 0.f, 0.f);
    if (q > 0) v0 = *reinterpret_cast<const float4*>(xrow - 4);   // left halo
    float4 v1 = *reinterpret_cast<const float4*>(xrow);
    float4 v2 = *reinterpret_cast<const float4*>(xrow + 4);
    float4 v3 = *reinterpret_cast<const float4*>(xrow + 8);
    float4 v4 = *reinterpret_cast<const float4*>(xrow + 12);
    if (q < 3) v5 = *reinterpret_cast<const float4*>(xrow + 16);  // right halo

    // y rows 0,1,66 are identically zero (zero-pad rows): fill while loads fly.
    if (t < 48) {
        int zr = t >> 4;
        zr = (zr == 2) ? 66 : zr;
        *reinterpret_cast<float4*>(&sm[zr * ST + ((t & 15) << 2)]) =
            make_float4(0.f, 0.f, 0.f, 0.f);
    }

    // xv[m] = x[rx][cq - 4 + m] (zero outside plane)
    float xv[24] = {
        v0.x, v0.y, v0.z, v0.w,  v1.x, v1.y, v1.z, v1.w,
        v2.x, v2.y, v2.z, v2.w,  v3.x, v3.y, v3.z, v3.w,
        v4.x, v4.y, v4.z, v4.w,  v5.x, v5.y, v5.z, v5.w };

    // y[rx+2][cq+u] = sum_j kwf[j] * x[rx][cq+u+j-2]  -> xv[u+2+j]
    float* yd = &sm[(rx + 2) * ST + cq];
    #pragma unroll
    for (int g = 0; g < 4; ++g) {
        float4 yq;
        float* yp = &yq.x;
        #pragma unroll
        for (int e = 0; e < 4; ++e) {
            const int u = g * 4 + e;
            yp[e] = fmaf(kw0, xv[u + 2],
                    fmaf(kw1, xv[u + 3],
                    fmaf(kw2, xv[u + 4], kw3 * xv[u + 5])));
        }
        *reinterpret_cast<float4*>(yd + 4 * g) = yq;
    }

    __syncthreads();

    // ---- colpass: thread t computes out[ty..ty+3][tx..tx+3] ----
    const int ty = (t >> 4) << 2;     // 0..60
    const int tx = (t & 15) << 2;     // 0..60

    float4 w[7];
    #pragma unroll
    for (int s = 0; s < 7; ++s)
        w[s] = *reinterpret_cast<const float4*>(&sm[(ty + s) * ST + tx]);

    #pragma unroll
    for (int r = 0; r < 4; ++r) {
        f32x4 o;
        o.x = fmaf(kh0, w[r].x, fmaf(kh1, w[r+1].x, fmaf(kh2, w[r+2].x, kh3 * w[r+3].x)));
        o.y = fmaf(kh0, w[r].y, fmaf(kh1, w[r+1].y, fmaf(kh2, w[r+2].y, kh3 * w[r+3].y)));
        o.z = fmaf(kh0, w[r].z, fmaf(kh1, w[r+1].z, fmaf(kh2, w[r+2].z, kh3 * w[r+3].z)));
        o.w = fmaf(kh0, w[r].w, fmaf(kh1, w[r+1].w, fmaf(kh2, w[r+2].w, kh3 * w[r+3].w)));
        __builtin_nontemporal_store(o,
            reinterpret_cast<f32x4*>(&op[(ty + r) * 64 + tx]));
    }
}

extern "C" void kernel_launch(void* const* d_in, const int* in_sizes, int n_in,
                              void* d_out, int out_size, void* d_ws, size_t ws_size,
                              hipStream_t stream)
{
    const float* x = (const float*)d_in[0];
    const float* k = (const float*)d_in[1];
    float* out = (float*)d_out;

    const int planes = 32 * 256;   // N*C
    Blur_910533066888_kernel<<<planes, 256, 0, stream>>>(x, k, out);
}